// Round 13
// baseline (9884.928 us; speedup 1.0000x reference)
//
#include <hip/hip_runtime.h>
#include <stdint.h>

typedef unsigned long long u64;

#define BATCH 32
#define NPTS  131072
#define KOUT  1024
#define NBLK  8                       // blocks per batch
#define TPB   512
#define PPT   (NPTS / (NBLK * TPB))   // 32 points per thread
#define NWAVES (TPB / 64)             // 8
#define NSLOT  (NBLK * NWAVES)        // 64 wave-level slots per batch

// Publication slot per (parity, batch, WAVE): three SELF-VALIDATING u64 words,
// each = (r<<32)|payload32, r = it+1. Reader polls with RELAXED agent loads
// until hi32==r on all three (per-word validity -> no acquire/release, no
// buffer_inv; proven rounds 8->11: 9.1ms -> 5.3ms). Parity reuse (r vs r-2)
// and 0xAA poison fail the tag check. Overwrite at r+2 is safe by causality:
// publishing r+2 requires having consumed all 64 slots of r+1, which requires
// every wave consumed r. No __syncthreads anywhere in the loop: waves
// self-synchronize purely through the slot protocol.
struct __align__(32) Slot {
    u64 w0;   // (r<<32) | hi32(f64 dist bits)
    u64 w1;   // (r<<32) | lo32(f64 dist bits)
    u64 w2;   // (r<<32) | best idx
    u64 pad;
};

__global__ __launch_bounds__(TPB, 2) void fps_kernel(
    const float* __restrict__ points,   // B*N*3 f32
    const int*   __restrict__ init_idx, // B
    float*       __restrict__ out,      // B*K*3 f32
    Slot*        __restrict__ slots)    // [2][BATCH][NSLOT]
{
    const int gid = blockIdx.x;
    // Swizzle: a batch's 8 blocks share gid%8 (likely same XCD). Bijective.
    const int b   = (gid >> 6) * 8 + (gid & 7);
    const int blk = (gid & 63) >> 3;
    const int tid = threadIdx.x;
    const int wid  = tid >> 6;
    const int lane = tid & 63;
    const float* bp = points + (size_t)b * NPTS * 3;

    // Persistent per-thread state: 32 points (f32) + 32 running dists (f64).
    float  px[PPT], py[PPT], pz[PPT];
    double dist[PPT];
    const int nbase = blk * (NPTS / NBLK) + tid;   // + j*TPB, strided for coalescing
#pragma unroll
    for (int j = 0; j < PPT; ++j) {
        int n = nbase + j * TPB;
        px[j]   = bp[(size_t)n * 3 + 0];
        py[j]   = bp[(size_t)n * 3 + 1];
        pz[j]   = bp[(size_t)n * 3 + 2];
        dist[j] = 1e10;   // INF
    }
    // Opacity barrier: forbid rematerialization as per-iteration global reloads
    // (round 7: 15 MB/iter re-fetch; verified fix round 8: 15.2 GB -> 37 MB).
#pragma unroll
    for (int j = 0; j < PPT; ++j) {
        asm volatile("" : "+v"(px[j]), "+v"(py[j]), "+v"(pz[j]));
    }

    const int last = init_idx[b];
    if (blk == 0 && tid < 3) {
        out[((size_t)b * KOUT) * 3 + tid] = bp[(size_t)last * 3 + tid];
    }
    float lx = bp[(size_t)last * 3 + 0];
    float ly = bp[(size_t)last * 3 + 1];
    float lz = bp[(size_t)last * 3 + 2];

    const int myslot = blk * NWAVES + wid;   // this wave's slot in [0,64)

    for (int it = 0; it < KOUT - 1; ++it) {
        const double lxd = (double)lx, lyd = (double)ly, lzd = (double)lz;

        // --- register-local dist update + argmax (f64, bit-identical to np float64;
        //     DO NOT alter the arithmetic expression tree — validated absmax 0.0 x4) ---
        double bestd = -1.0;
        int    besti = 0;
#pragma unroll
        for (int j = 0; j < PPT; ++j) {
            double dx = (double)px[j] - lxd;
            double dy = (double)py[j] - lyd;
            double dz = (double)pz[j] - lzd;
            double d2 = dx * dx + dy * dy + dz * dz;
            double nd = fmin(dist[j], d2);
            dist[j] = nd;
            if (nd > bestd) { bestd = nd; besti = nbase + j * TPB; }  // first max
        }

        // --- wave butterfly reduce (64 lanes), (dist,idx) lexicographic ---
#pragma unroll
        for (int off = 32; off > 0; off >>= 1) {
            double od = __shfl_xor(bestd, off, 64);
            int    oi = __shfl_xor(besti, off, 64);
            if (od > bestd || (od == bestd && oi < besti)) { bestd = od; besti = oi; }
        }

        const u64 r  = (u64)(uint32_t)(it + 1);
        const u64 rh = r << 32;
        Slot* sb = &slots[((size_t)(it & 1) * BATCH + b) * NSLOT];

        // --- publish this wave's candidate (lane 0), relaxed self-validating words ---
        if (lane == 0) {
            Slot* s = sb + myslot;
            u64 d64 = (u64)__double_as_longlong(bestd);
            __hip_atomic_store(&s->w0, rh | (d64 >> 32),
                               __ATOMIC_RELAXED, __HIP_MEMORY_SCOPE_AGENT);
            __hip_atomic_store(&s->w1, rh | (d64 & 0xFFFFFFFFull),
                               __ATOMIC_RELAXED, __HIP_MEMORY_SCOPE_AGENT);
            __hip_atomic_store(&s->w2, rh | (u64)(uint32_t)besti,
                               __ATOMIC_RELAXED, __HIP_MEMORY_SCOPE_AGENT);
        }
        // Publish must not sink past the poll loop (a lane of THIS wave polls our
        // own slot): compiler barrier + drain stores before polling.
        asm volatile("s_waitcnt vmcnt(0)" ::: "memory");

        // --- every wave: lane L polls slot L, then 64-way butterfly -> winner in
        //     ALL lanes of ALL waves. No LDS, no __syncthreads. ---
        {
            Slot* s = sb + lane;
            u64 a, c, d;
            do {
                a = __hip_atomic_load(&s->w0, __ATOMIC_RELAXED, __HIP_MEMORY_SCOPE_AGENT);
                c = __hip_atomic_load(&s->w1, __ATOMIC_RELAXED, __HIP_MEMORY_SCOPE_AGENT);
                d = __hip_atomic_load(&s->w2, __ATOMIC_RELAXED, __HIP_MEMORY_SCOPE_AGENT);
            } while (((a >> 32) != r) | ((c >> 32) != r) | ((d >> 32) != r));
            u64 gd = (a << 32) | (c & 0xFFFFFFFFull);   // f64 bits; >=0 so u64 cmp == f64 cmp
            int gi = (int)(uint32_t)d;
            // speculative coord fetch for this candidate (read-only data);
            // winner's coords selected by the butterfly below.
            float gx = bp[(size_t)gi * 3 + 0];
            float gy = bp[(size_t)gi * 3 + 1];
            float gz = bp[(size_t)gi * 3 + 2];
#pragma unroll
            for (int off = 32; off > 0; off >>= 1) {
                u64   od = (u64)__shfl_xor((long long)gd, off, 64);
                int   oi = __shfl_xor(gi, off, 64);
                float ox = __shfl_xor(gx, off, 64);
                float oy = __shfl_xor(gy, off, 64);
                float oz = __shfl_xor(gz, off, 64);
                if (od > gd || (od == gd && oi < gi)) {
                    gd = od; gi = oi; gx = ox; gy = oy; gz = oz;
                }
            }
            lx = gx; ly = gy; lz = gz;
            if (blk == 0 && tid == 0) {
                size_t o_ = ((size_t)b * KOUT + (it + 1)) * 3;
                out[o_ + 0] = gx; out[o_ + 1] = gy; out[o_ + 2] = gz;
            }
        }
    }
}

extern "C" void kernel_launch(void* const* d_in, const int* in_sizes, int n_in,
                              void* d_out, int out_size, void* d_ws, size_t ws_size,
                              hipStream_t stream) {
    const float* points   = (const float*)d_in[0];
    const int*   init_idx = (const int*)d_in[1];
    float*       out      = (float*)d_out;
    Slot*        slots    = (Slot*)d_ws;   // 2*32*64*32 B = 128 KB

    void* args[] = { (void*)&points, (void*)&init_idx, (void*)&out, (void*)&slots };
    // Cooperative launch solely for the co-residency guarantee (no grid.sync used).
    hipLaunchCooperativeKernel((const void*)fps_kernel,
                               dim3(BATCH * NBLK), dim3(TPB),
                               args, 0, stream);
}

// Round 14
// 5750.455 us; speedup vs baseline: 1.7190x; 1.7190x over previous
//
#include <hip/hip_runtime.h>
#include <stdint.h>

typedef unsigned long long u64;

#define BATCH 32
#define NPTS  131072
#define KOUT  1024
#define NBLK  8                       // blocks per batch
#define TPB   512
#define PPT   (NPTS / (NBLK * TPB))   // 32 points per thread
#define NWAVES (TPB / 64)             // 8

// Global publication slot per (parity, batch, block): three SELF-VALIDATING
// u64 words, each = (r<<32)|payload32. Relaxed agent atomics only (proven
// rounds 8->11). Parity reuse and 0xAA poison fail the tag check; overwrite
// at r+2 excluded by consumption causality.
struct __align__(32) Slot {
    u64 w0;   // (r<<32) | hi32(f64 dist bits)
    u64 w1;   // (r<<32) | lo32(f64 dist bits)
    u64 w2;   // (r<<32) | best idx
    u64 pad;
};

__global__ __launch_bounds__(TPB, 2) void fps_kernel(
    const float* __restrict__ points,   // B*N*3 f32
    const int*   __restrict__ init_idx, // B
    float*       __restrict__ out,      // B*K*3 f32
    Slot*        __restrict__ slots)    // [2][BATCH][NBLK]
{
    const int gid = blockIdx.x;
    // Swizzle: a batch's 8 blocks share gid%8 (likely same XCD). Bijective.
    const int b   = (gid >> 6) * 8 + (gid & 7);
    const int blk = (gid & 63) >> 3;
    const int tid = threadIdx.x;
    const int wid  = tid >> 6;
    const int lane = tid & 63;
    const float* bp = points + (size_t)b * NPTS * 3;

    // Persistent per-thread state: 32 points (f32) + 32 running dists (f64).
    float  px[PPT], py[PPT], pz[PPT];
    double dist[PPT];
    const int nbase = blk * (NPTS / NBLK) + tid;   // + j*TPB, strided for coalescing
#pragma unroll
    for (int j = 0; j < PPT; ++j) {
        int n = nbase + j * TPB;
        px[j]   = bp[(size_t)n * 3 + 0];
        py[j]   = bp[(size_t)n * 3 + 1];
        pz[j]   = bp[(size_t)n * 3 + 2];
        dist[j] = 1e10;   // INF
    }
    // Opacity barrier: forbid rematerialization as per-iteration global reloads
    // (round 7: 15 MB/iter re-fetch; verified fix round 8: 15.2 GB -> 37 MB).
#pragma unroll
    for (int j = 0; j < PPT; ++j) {
        asm volatile("" : "+v"(px[j]), "+v"(py[j]), "+v"(pz[j]));
    }

    // LDS handshake state: tag-validated, workgroup-scope acquire/release only
    // (compiles to ds ops + lgkmcnt waits — no L2 maintenance, unlike agent scope).
    // NO __syncthreads inside the iteration loop.
    __shared__ u64      s_in_d[NWAVES];   // wave-best f64 bits
    __shared__ int      s_in_i[NWAVES];   // wave-best idx
    __shared__ uint32_t s_in_tag[NWAVES];
    __shared__ float    s_out_x, s_out_y, s_out_z;
    __shared__ uint32_t s_out_tag;

    if (tid < NWAVES) s_in_tag[tid] = 0;   // fresh LDS is undefined: must init tags
    if (tid == 0)     s_out_tag = 0;
    __syncthreads();   // once, OUTSIDE the loop

    const int last = init_idx[b];
    if (blk == 0 && tid < 3) {
        out[((size_t)b * KOUT) * 3 + tid] = bp[(size_t)last * 3 + tid];
    }
    float lx = bp[(size_t)last * 3 + 0];
    float ly = bp[(size_t)last * 3 + 1];
    float lz = bp[(size_t)last * 3 + 2];

    for (int it = 0; it < KOUT - 1; ++it) {
        const double lxd = (double)lx, lyd = (double)ly, lzd = (double)lz;

        // --- register-local dist update + argmax (f64, bit-identical to np float64;
        //     DO NOT alter the arithmetic expression tree — validated absmax 0.0 x5) ---
        double bestd = -1.0;
        int    besti = 0;
#pragma unroll
        for (int j = 0; j < PPT; ++j) {
            double dx = (double)px[j] - lxd;
            double dy = (double)py[j] - lyd;
            double dz = (double)pz[j] - lzd;
            double d2 = dx * dx + dy * dy + dz * dz;
            double nd = fmin(dist[j], d2);
            dist[j] = nd;
            if (nd > bestd) { bestd = nd; besti = nbase + j * TPB; }  // first max
        }

        // --- wave butterfly reduce (64 lanes), (dist,idx) lexicographic ---
#pragma unroll
        for (int off = 32; off > 0; off >>= 1) {
            double od = __shfl_xor(bestd, off, 64);
            int    oi = __shfl_xor(besti, off, 64);
            if (od > bestd || (od == bestd && oi < besti)) { bestd = od; besti = oi; }
        }

        const uint32_t r = (uint32_t)(it + 1);

        // --- wave -> block: LDS publish, release-tagged (cheap, intra-CU) ---
        if (lane == 0) {
            s_in_d[wid] = (u64)__double_as_longlong(bestd);
            s_in_i[wid] = besti;
            __hip_atomic_store(&s_in_tag[wid], r, __ATOMIC_RELEASE,
                               __HIP_MEMORY_SCOPE_WORKGROUP);
        }

        float gx, gy, gz;
        if (wid == 0) {
            const int src = lane & 7;
            // collect the 8 wave candidates (tags spin; acquire orders data reads)
            uint32_t t;
            do {
                t = __hip_atomic_load(&s_in_tag[src], __ATOMIC_ACQUIRE,
                                      __HIP_MEMORY_SCOPE_WORKGROUP);
            } while (t != r);
            u64 vd = s_in_d[src];
            int vi = s_in_i[src];
            // butterfly over 8 candidates (x8 replicated); u64 cmp == f64 cmp (dist>=0)
#pragma unroll
            for (int off = 4; off > 0; off >>= 1) {
                u64 od = (u64)__shfl_xor((long long)vd, off, 64);
                int oi = __shfl_xor(vi, off, 64);
                if (od > vd || (od == vd && oi < vi)) { vd = od; vi = oi; }
            }
            // publish block candidate globally: relaxed self-validating words
            const u64 rh = (u64)r << 32;
            Slot* sb = &slots[((size_t)(it & 1) * BATCH + b) * NBLK];
            if (lane == 0) {
                Slot* s = sb + blk;
                __hip_atomic_store(&s->w0, rh | (vd >> 32),
                                   __ATOMIC_RELAXED, __HIP_MEMORY_SCOPE_AGENT);
                __hip_atomic_store(&s->w1, rh | (vd & 0xFFFFFFFFull),
                                   __ATOMIC_RELAXED, __HIP_MEMORY_SCOPE_AGENT);
                __hip_atomic_store(&s->w2, rh | (u64)(uint32_t)vi,
                                   __ATOMIC_RELAXED, __HIP_MEMORY_SCOPE_AGENT);
            }
            // publish must not sink past our own poll (we poll our own slot too)
            asm volatile("s_waitcnt vmcnt(0)" ::: "memory");
            // poll the 8 block slots (lanes replicated x8 -> butterfly needs no bcast)
            Slot* s = sb + src;
            u64 a, c, d;
            do {
                a = __hip_atomic_load(&s->w0, __ATOMIC_RELAXED, __HIP_MEMORY_SCOPE_AGENT);
                c = __hip_atomic_load(&s->w1, __ATOMIC_RELAXED, __HIP_MEMORY_SCOPE_AGENT);
                d = __hip_atomic_load(&s->w2, __ATOMIC_RELAXED, __HIP_MEMORY_SCOPE_AGENT);
            } while (((a >> 32) != r) | ((c >> 32) != r) | ((d >> 32) != r));
            u64 gd = (a << 32) | (c & 0xFFFFFFFFull);
            int gi = (int)(uint32_t)d;
            // speculative coord fetch (read-only data); winner picked by butterfly
            gx = bp[(size_t)gi * 3 + 0];
            gy = bp[(size_t)gi * 3 + 1];
            gz = bp[(size_t)gi * 3 + 2];
#pragma unroll
            for (int off = 4; off > 0; off >>= 1) {
                u64   od = (u64)__shfl_xor((long long)gd, off, 64);
                int   oi = __shfl_xor(gi, off, 64);
                float ox = __shfl_xor(gx, off, 64);
                float oy = __shfl_xor(gy, off, 64);
                float oz = __shfl_xor(gz, off, 64);
                if (od > gd || (od == gd && oi < gi)) {
                    gd = od; gi = oi; gx = ox; gy = oy; gz = oz;
                }
            }
            // block broadcast via LDS tag (replaces syncthreads B + s_last)
            if (lane == 0) {
                s_out_x = gx; s_out_y = gy; s_out_z = gz;
                __hip_atomic_store(&s_out_tag, r, __ATOMIC_RELEASE,
                                   __HIP_MEMORY_SCOPE_WORKGROUP);
                if (blk == 0) {
                    size_t o_ = ((size_t)b * KOUT + (it + 1)) * 3;
                    out[o_ + 0] = gx; out[o_ + 1] = gy; out[o_ + 2] = gz;
                }
            }
        } else {
            // waves 1..7: wait for wave 0's broadcast (LDS spin, no global traffic)
            uint32_t t;
            do {
                t = __hip_atomic_load(&s_out_tag, __ATOMIC_ACQUIRE,
                                      __HIP_MEMORY_SCOPE_WORKGROUP);
            } while (t != r);
            gx = s_out_x; gy = s_out_y; gz = s_out_z;
        }
        lx = gx; ly = gy; lz = gz;
    }
}

extern "C" void kernel_launch(void* const* d_in, const int* in_sizes, int n_in,
                              void* d_out, int out_size, void* d_ws, size_t ws_size,
                              hipStream_t stream) {
    const float* points   = (const float*)d_in[0];
    const int*   init_idx = (const int*)d_in[1];
    float*       out      = (float*)d_out;
    Slot*        slots    = (Slot*)d_ws;   // 2*32*8*32 B = 16 KB

    void* args[] = { (void*)&points, (void*)&init_idx, (void*)&out, (void*)&slots };
    // Cooperative launch solely for the co-residency guarantee (no grid.sync used).
    hipLaunchCooperativeKernel((const void*)fps_kernel,
                               dim3(BATCH * NBLK), dim3(TPB),
                               args, 0, stream);
}